// Round 20
// baseline (372.753 us; speedup 1.0000x reference)
//
#include <hip/hip_runtime.h>
#include <hip/hip_bf16.h>

#define BT    16384
#define NVAR  16
#define DDIM  64
#define FDIM  1024
#define HDIM  256
#define ODIM  256
#define CDIM  64

typedef __bf16 bf16x8 __attribute__((ext_vector_type(8)));
typedef __bf16 bf16x4 __attribute__((ext_vector_type(4)));
typedef float  f32x4  __attribute__((ext_vector_type(4)));

__device__ __forceinline__ void gload16(const void* g, void* l) {
    __builtin_amdgcn_global_load_lds((const __attribute__((address_space(1))) void*)g,
                                     (__attribute__((address_space(3))) void*)l, 16, 0, 0);
}

// ---------------------------------------------------------------------------
// bf16 MFMA GEMM (128x128 tile, BK=64, 4 waves). AF32: A f32 reg-staged.
// Split-output: cols >= splitCol -> C2. z-batched.
// ---------------------------------------------------------------------------
template<int AF32>
__global__ __launch_bounds__(256)
void gemm_mfma(const void* __restrict__ Araw, const __bf16* __restrict__ Bt,
               const float* __restrict__ bias, const float* __restrict__ bias2,
               __bf16* __restrict__ C, __bf16* __restrict__ C2,
               int K, int lda, int ldb, int ldc, int ldc2,
               const float* __restrict__ rowAdd, int act, int splitCol,
               long zA, long zB, long zC)
{
    __shared__ char smem[32768];
    char* As = smem;
    char* Bs = smem + 16384;

    const int z = blockIdx.z;
    const __bf16* Btz = Bt + z * zB;

    const int tid  = threadIdx.x;
    const int lane = tid & 63;
    const int wid  = tid >> 6;
    const int wr   = wid >> 1, wc = wid & 1;
    const int lr   = lane & 15, lc = lane >> 4;
    const long row0 = (long)blockIdx.y * 128;
    const int  col0 = blockIdx.x * 128;
    const int ldsbase = (tid & ~63) << 4;

    f32x4 acc[4][4] = {};
    int rA[4], rB[4];
#pragma unroll
    for (int i = 0; i < 4; ++i) { rA[i] = wr * 64 + i * 16 + lr; rB[i] = wc * 64 + i * 16 + lr; }

    const int nk = K >> 6;
    for (int kt = 0; kt < nk; ++kt) {
        const int k0 = kt << 6;
        __syncthreads();
#pragma unroll
        for (int s = 0; s < 4; ++s) {
            int q  = s * 256 + tid;
            int r  = q >> 3, cs = q & 7;
            int cg = cs ^ (r & 7);
            if (AF32 != 0) {
                const float* src = (const float*)Araw + z * zA + (row0 + r) * (long)lda + k0 + (cg << 3);
                float4 u0 = *(const float4*)src;
                float4 u1 = *(const float4*)(src + 4);
                bf16x8 o;
                o[0] = (__bf16)u0.x; o[1] = (__bf16)u0.y; o[2] = (__bf16)u0.z; o[3] = (__bf16)u0.w;
                o[4] = (__bf16)u1.x; o[5] = (__bf16)u1.y; o[6] = (__bf16)u1.z; o[7] = (__bf16)u1.w;
                *(bf16x8*)(As + q * 16) = o;
            } else {
                gload16((const __bf16*)Araw + z * zA + (row0 + r) * (long)lda + k0 + (cg << 3),
                        As + (s << 12) + ldsbase);
            }
            gload16(Btz + (long)(col0 + r) * ldb + k0 + (cg << 3), Bs + (s << 12) + ldsbase);
        }
        __syncthreads();
#pragma unroll
        for (int ks = 0; ks < 2; ++ks) {
            bf16x8 af[4], bfr[4];
#pragma unroll
            for (int i = 0; i < 4; ++i) {
                int c = ks * 4 + lc;
                af[i]  = *(const bf16x8*)(As + rA[i] * 128 + ((c ^ (rA[i] & 7)) << 4));
                bfr[i] = *(const bf16x8*)(Bs + rB[i] * 128 + ((c ^ (rB[i] & 7)) << 4));
            }
#pragma unroll
            for (int i = 0; i < 4; ++i)
#pragma unroll
                for (int j = 0; j < 4; ++j)
                    acc[i][j] = __builtin_amdgcn_mfma_f32_16x16x32_bf16(af[i], bfr[j], acc[i][j], 0, 0, 0);
        }
    }

#pragma unroll
    for (int j = 0; j < 4; ++j) {
        int col = col0 + wc * 64 + j * 16 + lr;
        bool hi = col >= splitCol;
        float bv = hi ? bias2[col - splitCol] : (bias ? bias[col] : 0.f);
#pragma unroll
        for (int i = 0; i < 4; ++i) {
            f32x4 v = acc[i][j];
#pragma unroll
            for (int q = 0; q < 4; ++q) {
                long row = row0 + wr * 64 + i * 16 + lc * 4 + q;
                float x = v[q] + bv;
                if (rowAdd && !hi) x += rowAdd[(row >> 8) * (long)ldc + col];
                if (act && !hi)    x = x > 0.f ? x : (__expf(x) - 1.f);
                if (hi) C2[z * zC + row * (long)ldc2 + (col - splitCol)] = (__bf16)x;
                else    C [z * zC + row * (long)ldc  + col]              = (__bf16)x;
            }
        }
    }
}

// ---------------------------------------------------------------------------
// misc_prep (fused): pad_skip | fgfuse | bfuse | ctxh | 3x transpose
// (W2cat copy removed: Wf GEMM now reads vg_W2/og_W2 directly in 2 calls)
// ---------------------------------------------------------------------------
__global__ __launch_bounds__(256)
void misc_prep(const float* __restrict__ fg_skipW, const float* __restrict__ fg_skipb,
               __bf16* __restrict__ Btk1, float* __restrict__ bias2,
               const float* __restrict__ fg_W2, const float* __restrict__ fg_Wg,
               const float* __restrict__ fg_b2, const float* __restrict__ fg_bg,
               float* __restrict__ fgWf, float* __restrict__ fgbf,
               const float* __restrict__ vg_b2, const float* __restrict__ vg_Wg,
               const float* __restrict__ vg_bg, const float* __restrict__ og_b2,
               const float* __restrict__ og_Wg, const float* __restrict__ og_bg,
               float* __restrict__ bWf, float* __restrict__ ogbWf,
               const float* __restrict__ ctx, const float* __restrict__ fg_Wc,
               float* __restrict__ ctxh,
               const float* __restrict__ fg_W1, __bf16* __restrict__ WgT)
{
    __shared__ float cs[4352];   // 17 KB: ctxh uses 4096; transposes use [32][33]
    int bx = blockIdx.x, tid = threadIdx.x;
    if (bx < 128) {                       // pad_skip
        int r = bx;
        for (int k = tid; k < 1024; k += 256)
            Btk1[(size_t)(256 + r) * 1024 + k] = (r < 16) ? (__bf16)fg_skipW[k * 16 + r] : (__bf16)0.f;
        if (tid == 0) bias2[r] = (r < 16) ? fg_skipb[r] : 0.f;
    } else if (bx < 160) {                // fgfuse
        int c = bx - 128, k = tid;
        float s = 0.f;
#pragma unroll
        for (int j = 0; j < 16; ++j) s = fmaf(fg_W2[k * 16 + j], fg_Wg[j * 32 + c], s);
        fgWf[k * 32 + c] = s;
        if (k == 0) {
            float t = fg_bg[c];
#pragma unroll
            for (int j = 0; j < 16; ++j) t = fmaf(fg_b2[j], fg_Wg[j * 32 + c], t);
            fgbf[c] = t;
        }
    } else if (bx < 194) {                // bfuse (34 blocks)
        int u = bx - 160;
        int n = u >> 1, c = (u & 1) * 256 + tid;
        const float* b2 = n < 16 ? vg_b2 + n * 256 : og_b2;
        const float* Wg = n < 16 ? vg_Wg + (size_t)n * 131072 : og_Wg;
        const float* bg = n < 16 ? vg_bg + n * 512 : og_bg;
        float* dst      = n < 16 ? bWf + n * 512 : ogbWf;
        float s = bg[c];
        for (int k = 0; k < 256; ++k) s = fmaf(b2[k], Wg[k * 512 + c], s);
        dst[c] = s;
    } else if (bx < 198) {                // ctxh (4 blocks of 64 cols)
        for (int i = tid; i < 4096; i += 256) cs[i] = ctx[i];
        __syncthreads();
        int col = (bx - 194) * 64 + (tid & 63);
        int r0 = (tid >> 6) * 16;
        for (int r = r0; r < r0 + 16; ++r) {
            float s = 0.f;
            for (int k = 0; k < 64; ++k) s = fmaf(cs[r * 64 + k], fg_Wc[k * 256 + col], s);
            ctxh[r * 256 + col] = s;
        }
    } else {                              // weight transposes (2432 blocks)
        int b2 = bx - 198;
        const float* in; __bf16* outp; int K, N, tilesN, tl;
        if (b2 < 2048) {                  // vg_Wg [z][256][512] -> WgT [z][512][256]
            int z = b2 >> 7; tl = b2 & 127;
            in = vg_Wg + (size_t)z * 131072; outp = WgT + (size_t)z * 131072;
            K = 256; N = 512; tilesN = 16;
        } else if (b2 < 2176) {           // og_Wg -> WgT[16]
            tl = b2 - 2048;
            in = og_Wg; outp = WgT + (size_t)16 * 131072;
            K = 256; N = 512; tilesN = 16;
        } else {                          // fg_W1 [1024][256] -> Btk1 rows 0..255
            tl = b2 - 2176;
            in = fg_W1; outp = Btk1;
            K = 1024; N = 256; tilesN = 8;
        }
        int tk = tl / tilesN, tn = tl % tilesN;
        float (*t)[33] = (float(*)[33])cs;
        int r = tid >> 3, c0 = (tid & 7) << 2;
        float4 v = *(const float4*)(in + (size_t)(tk * 32 + r) * N + tn * 32 + c0);
        t[r][c0] = v.x; t[r][c0 + 1] = v.y; t[r][c0 + 2] = v.z; t[r][c0 + 3] = v.w;
        __syncthreads();
        int nn = tid >> 3, k4 = (tid & 7) << 2;
        bf16x4 o;
        o[0] = (__bf16)t[k4 + 0][nn]; o[1] = (__bf16)t[k4 + 1][nn];
        o[2] = (__bf16)t[k4 + 2][nn]; o[3] = (__bf16)t[k4 + 3][nn];
        *(bf16x4*)(outp + (size_t)(tn * 32 + nn) * K + tk * 32 + k4) = o;
    }
}

// ---------------------------------------------------------------------------
// frag_pack_all: 4 tiles/block (one per wave). t<4352: Wfb->Wfp (z 0..16);
// t<5376: W1S pack; t<5504: og_W1 pack.
// ---------------------------------------------------------------------------
__global__ __launch_bounds__(256)
void frag_pack_all(const __bf16* __restrict__ Wfb, __bf16* __restrict__ Wfp,
                   const float* __restrict__ vg_W1, const float* __restrict__ vg_skipW,
                   __bf16* __restrict__ W1Sp,
                   const float* __restrict__ og_W1, __bf16* __restrict__ ogW1p)
{
    int t = blockIdx.x * 4 + (threadIdx.x >> 6);
    int lane = threadIdx.x & 63, lr = lane & 15, lc = lane >> 4;
    if (t < 4352) {
        int z = t >> 8, b = t & 255;
        int nt = b >> 3, kt = b & 7;
        const __bf16* src = Wfb + (size_t)z * 131072;
        bf16x8 o;
#pragma unroll
        for (int e = 0; e < 8; ++e)
            o[e] = src[(size_t)(kt * 32 + lc * 8 + e) * 512 + nt * 16 + lr];
        *(bf16x8*)&Wfp[(size_t)z * 131072 + (size_t)b * 512 + lane * 8] = o;
    } else if (t < 5376) {
        int u = t - 4352; int n = u >> 6, b = u & 63;
        int nt = b >> 1, kt = b & 1;
        const float* src = (nt < 16) ? vg_W1 + (size_t)n * 16384 : vg_skipW + (size_t)n * 16384;
        int col = (nt & 15) * 16 + lr;
        bf16x8 o;
#pragma unroll
        for (int e = 0; e < 8; ++e)
            o[e] = (__bf16)src[(size_t)(kt * 32 + lc * 8 + e) * 256 + col];
        *(bf16x8*)&W1Sp[((size_t)n * 64 + b) * 512 + lane * 8] = o;
    } else if (t < 5504) {
        int b = t - 5376;
        int nt = b >> 3, kt = b & 7;
        bf16x8 o;
#pragma unroll
        for (int e = 0; e < 8; ++e)
            o[e] = (__bf16)og_W1[(size_t)(kt * 32 + lc * 8 + e) * 256 + nt * 16 + lr];
        *(bf16x8*)&ogW1p[(size_t)b * 512 + lane * 8] = o;
    }
}

// ---------------------------------------------------------------------------
// K2: g = h1@fgWf + skip16; LN16 + softmax16 -> w. 4 rows/block.
// ---------------------------------------------------------------------------
__global__ __launch_bounds__(256)
void k2_logits(const __bf16* __restrict__ h1, const __bf16* __restrict__ skip16,
               const float* __restrict__ Wf, const float* __restrict__ bf,
               const float* __restrict__ gamma, const float* __restrict__ beta,
               float* __restrict__ wout)
{
    __shared__ float hrow[4][256];
    int l = threadIdx.x & 63, wv_ = threadIdx.x >> 6;
    long row = (long)blockIdx.x * 4 + wv_;

    bf16x4 hv = *(const bf16x4*)(h1 + row * 256 + l * 4);
    float4 hf; hf.x = (float)hv[0]; hf.y = (float)hv[1]; hf.z = (float)hv[2]; hf.w = (float)hv[3];
    *(float4*)&hrow[wv_][l * 4] = hf;

    int cc = l & 31, half = l >> 5;
    float g = 0.f;
    int kb = half * 128;
#pragma unroll 4
    for (int k = kb; k < kb + 128; ++k)
        g = fmaf(hrow[wv_][k], Wf[k * 32 + cc], g);
    g += __shfl_xor(g, 32);
    g += bf[cc];

    int c = l & 15;
    float a2    = __shfl(g, c);
    float gate2 = __shfl(g, c + 16);
    float skip  = (float)skip16[row * 128 + c];
    float sv = skip + a2 * (1.f / (1.f + __expf(-gate2)));

    float sum = sv, sq = sv * sv;
#pragma unroll
    for (int m = 1; m < 16; m <<= 1) {
        sum += __shfl_xor(sum, m);
        sq  += __shfl_xor(sq, m);
    }
    float mean = sum * (1.f / 16.f);
    float var  = sq * (1.f / 16.f) - mean * mean;
    float logit = (sv - mean) * rsqrtf(var + 1e-5f) * gamma[c] + beta[c];

    float mx = logit;
#pragma unroll
    for (int m = 1; m < 16; m <<= 1) mx = fmaxf(mx, __shfl_xor(mx, m));
    float e = __expf(logit - mx);
    float es = e;
#pragma unroll
    for (int m = 1; m < 16; m <<= 1) es += __shfl_xor(es, m);
    if (l < 16) wout[row * NVAR + l] = e / es;
}

// hbuf swizzle: full 32-bank spread (adds row bit-3 into chunk XOR)
#define HCHUNK(c, r) ((c) ^ ((r) & 7) ^ ((((r) >> 3) & 1) << 1))

// ---------------------------------------------------------------------------
// MEGA v16 (R19, passing, 289 us): 1 barrier/n pipeline, weight dbuf,
// cross-barrier wb0 prefetch, vectorized LN reads, 32-bank hbuf swizzle.
// ---------------------------------------------------------------------------
__global__ __launch_bounds__(512, 2)
void vsn_mega(const float* __restrict__ vars, const float* __restrict__ wsm,
              const __bf16* __restrict__ W1Sp, const __bf16* __restrict__ Wfp,
              const float* __restrict__ vg_b1, const float* __restrict__ vg_skipb,
              const float* __restrict__ bWf,
              const float* __restrict__ vg_gamma, const float* __restrict__ vg_beta,
              const __bf16* __restrict__ ogW1p, const __bf16* __restrict__ ogWfp,
              const float* __restrict__ og_b1, const float* __restrict__ ogbWf,
              const float* __restrict__ og_gamma, const float* __restrict__ og_beta,
              float* __restrict__ out)
{
    __shared__ __bf16 xb[2][32 * 64];      //  8 KB
    __shared__ __bf16 hbuf[2][32 * 256];   // 32 KB
    __shared__ float  red2[2][32][8][2];   //  4 KB
    __shared__ float  wls[32 * 16];        //  2 KB   => ~46 KB

    const int tid = threadIdx.x;
    const int w   = tid >> 6, lane = tid & 63;
    const int lr  = lane & 15, lc = lane >> 4;
    const long row0 = (long)blockIdx.x * 32;

    wls[tid] = wsm[row0 * 16 + tid];

    f32x4 selv[2][2] = {};    // [j][i]
    f32x4 skipv[2][2];        // [j][i] skip(n) carried across one barrier
    f32x4 comb[2][2];         // [j][i] combined(n) carried across one barrier
    bf16x8 wb[2][4];          // GEMM2 weight dbuf; wb[0] prefetched across barrier

    const int sr = tid >> 4, sc = tid & 15;
    const int shalf = sc & 1;
    const int scg = (sc >> 1) ^ (sr & 7);
    const float* xrow = vars + (row0 + sr) * FDIM + sc * 4;

    auto stage_xb = [&](int buf, float4 v) {
        bf16x4 o;
        o[0]=(__bf16)v.x; o[1]=(__bf16)v.y; o[2]=(__bf16)v.z; o[3]=(__bf16)v.w;
        *(bf16x4*)&xb[buf][sr * 64 + scg * 8 + shalf * 4] = o;
    };

    auto prefetch_wb0 = [&](int nn) {
        const __bf16* wfb = Wfp + (size_t)nn * 131072;
#pragma unroll
        for (int t = 0; t < 4; ++t) {
            int nt = (t < 2) ? (w * 2 + t) : (16 + w * 2 + (t - 2));
            wb[0][t] = *(const bf16x8*)&wfb[(size_t)(nt * 8 + 0) * 512 + lane * 8];
        }
    };

    // GEMM1(nn): read xb[buf] -> hbuf[buf] (elu) + skipv (regs)
    auto do_gemm1 = [&](int nn, int buf) {
        const __bf16* w1b = W1Sp + (size_t)nn * 32768;
        f32x4 accS[2][2] = {}, accH[2][2] = {};
#pragma unroll
        for (int kt = 0; kt < 2; ++kt) {
            bf16x8 wh0 = *(const bf16x8*)&w1b[(size_t)(((w * 2 + 0) * 2 + kt)) * 512 + lane * 8];
            bf16x8 wh1 = *(const bf16x8*)&w1b[(size_t)(((w * 2 + 1) * 2 + kt)) * 512 + lane * 8];
            bf16x8 ws0 = *(const bf16x8*)&w1b[(size_t)(((16 + w * 2 + 0) * 2 + kt)) * 512 + lane * 8];
            bf16x8 ws1 = *(const bf16x8*)&w1b[(size_t)(((16 + w * 2 + 1) * 2 + kt)) * 512 + lane * 8];
            bf16x8 af[2];
#pragma unroll
            for (int i = 0; i < 2; ++i) {
                int r = i * 16 + lr;
                int kc = (kt * 4 + lc) ^ (r & 7);
                af[i] = *(const bf16x8*)&xb[buf][r * 64 + kc * 8];
            }
            __builtin_amdgcn_s_setprio(1);
#pragma unroll
            for (int i = 0; i < 2; ++i) {
                accH[0][i] = __builtin_amdgcn_mfma_f32_16x16x32_bf16(af[i], wh0, accH[0][i], 0, 0, 0);
                accH[1][i] = __builtin_amdgcn_mfma_f32_16x16x32_bf16(af[i], wh1, accH[1][i], 0, 0, 0);
                accS[0][i] = __builtin_amdgcn_mfma_f32_16x16x32_bf16(af[i], ws0, accS[0][i], 0, 0, 0);
                accS[1][i] = __builtin_amdgcn_mfma_f32_16x16x32_bf16(af[i], ws1, accS[1][i], 0, 0, 0);
            }
            __builtin_amdgcn_s_setprio(0);
        }
        const float* b1 = vg_b1 + nn * 256;
        const float* sb = vg_skipb + nn * 256;
#pragma unroll
        for (int j = 0; j < 2; ++j) {
            int col = w * 32 + j * 16 + lr;
            float bh = b1[col], bs = sb[col];
#pragma unroll
            for (int i = 0; i < 2; ++i)
#pragma unroll
                for (int q = 0; q < 4; ++q) {
                    int row = i * 16 + lc * 4 + q;
                    float x = accH[j][i][q] + bh;
                    x = x > 0.f ? x : (__expf(x) - 1.f);
                    hbuf[buf][row * 256 + (HCHUNK(col >> 3, row) << 3) + (col & 7)] = (__bf16)x;
                    skipv[j][i][q] = accS[j][i][q] + bs;
                }
        }
    };

    // ---- prologue ----
    float4 xv = *(const float4*)(xrow);                 // x(0)
    stage_xb(0, xv);
    float4 xv1 = *(const float4*)(xrow + DDIM);         // x(1)
    __syncthreads();
    do_gemm1(0, 0);
    stage_xb(1, xv1);
    float4 xp = *(const float4*)(xrow + 2 * DDIM);      // x(2)
    prefetch_wb0(0);                                    // GEMM2(0) kt=0 weights
    __syncthreads();

    // ---- main pipeline: one barrier per n ----
    for (int n = 0; n < NVAR; ++n) {
        const int cur = n & 1, nxt = cur ^ 1;

        // 1. LN(n-1): red2[nxt] + comb -> selv
        if (n > 0) {
            const int pn = n - 1;
            const float* gma = vg_gamma + pn * 256;
            const float* bta = vg_beta + pn * 256;
#pragma unroll
            for (int i = 0; i < 2; ++i)
#pragma unroll
                for (int q = 0; q < 4; ++q) {
                    int row = i * 16 + lc * 4 + q;
                    const float4* rp = (const float4*)&red2[nxt][row][0][0];
                    float4 r0 = rp[0], r1 = rp[1], r2 = rp[2], r3 = rp[3];
                    float s  = r0.x + r0.z + r1.x + r1.z + r2.x + r2.z + r3.x + r3.z;
                    float ss = r0.y + r0.w + r1.y + r1.w + r2.y + r2.w + r3.y + r3.w;
                    float mean = s * (1.f / 256.f);
                    float var  = ss * (1.f / 256.f) - mean * mean;
                    float rstd = rsqrtf(var + 1e-5f);
                    float wv = wls[row * 16 + pn];
#pragma unroll
                    for (int j = 0; j < 2; ++j) {
                        int col = w * 32 + j * 16 + lr;
                        float pv = (comb[j][i][q] - mean) * rstd * gma[col] + bta[col];
                        selv[j][i][q] += wv * pv;
                    }
                }
        }

        // 2. GEMM2(n): hbuf[cur] @ Wf_n -> aA/aG  (wb[0] prefetched pre-barrier)
        {
            const __bf16* wfb = Wfp + (size_t)n * 131072;
            f32x4 aA[2][2] = {}, aG[2][2] = {};
#pragma unroll
            for (int kt = 0; kt < 8; ++kt) {
                const int cb = kt & 1, nb = cb ^ 1;
                if (kt < 7) {
#pragma unroll
                    for (int t = 0; t < 4; ++t) {
                        int nt = (t < 2) ? (w * 2 + t) : (16 + w * 2 + (t - 2));
                        wb[nb][t] = *(const bf16x8*)&wfb[(size_t)(nt * 8 + kt + 1) * 512 + lane * 8];
                    }
                }
                bf16x8 af[2];
#pragma unroll
                for (int i = 0; i < 2; ++i) {
                    int r = i * 16 + lr;
                    int kc = HCHUNK(kt * 4 + lc, r);
                    af[i] = *(const bf16x8*)&hbuf[cur][r * 256 + kc * 8];
                }
                __builtin_amdgcn_s_setprio(1);
#pragma unroll
                for (int i = 0; i < 2; ++i) {
                    aA[0][i] = __builtin_amdgcn_mfma_f32_16x16x32_bf16(af[i], wb[cb][0], aA[0][i], 0, 0, 0);
                    aA[1][i] = __builtin_amdgcn_mfma_f32_16x16x32_bf16(af[i], wb[cb][1], aA[1][i], 0, 0, 0);
                    aG[0][i] = __builtin_amdgcn_mfma_f32_16x16x32_bf16(af[i], wb[cb][2], aG[0][i], 0, 0, 0);
                    aG[1][i] = __builtin_amdgcn_mfma_f32_16x16x32_bf16(af[i], wb[cb][3], aG[1][i], 0, 0, 0);
                }
                __builtin_amdgcn_s_setprio(0);
            }
            // 3. combine with skipv(n); comb(n) = result; reduce -> red2[cur]
            const float* bW = bWf + n * 512;
#pragma unroll
            for (int j = 0; j < 2; ++j) {
                int col = w * 32 + j * 16 + lr;
                float ba_ = bW[col], bg_ = bW[col + 256];
#pragma unroll
                for (int i = 0; i < 2; ++i)
#pragma unroll
                    for (int q = 0; q < 4; ++q) {
                        float av = aA[j][i][q] + ba_;
                        float gv = aG[j][i][q] + bg_;
                        comb[j][i][q] = skipv[j][i][q] + av * (1.f / (1.f + __expf(-gv)));
                    }
            }
#pragma unroll
            for (int i = 0; i < 2; ++i)
#pragma unroll
                for (int q = 0; q < 4; ++q) {
                    float s = comb[0][i][q] + comb[1][i][q];
                    float ss = comb[0][i][q] * comb[0][i][q] + comb[1][i][q] * comb[1][i][q];
                    s += __shfl_xor(s, 1); ss += __shfl_xor(ss, 1);
                    s += __shfl_xor(s, 2); ss += __shfl_xor(ss, 2);
                    s += __shfl_xor(s, 4); ss += __shfl_xor(ss, 4);
                    s += __shfl_xor(s, 8); ss += __shfl_xor(ss, 8);
                    if (lr == 0) {
                        int row = i * 16 + lc * 4 + q;
                        red2[cur][row][w][0] = s; red2[cur][row][w][1] = ss;
                    }
                }
        }

        // 5. GEMM1(n+1) -> hbuf[nxt], skipv(n+1)
        if (n < NVAR - 1) do_gemm1(n + 1, nxt);

        // 6. stage x(n+2) into xb[cur]; prefetch x(n+3); prefetch wb[0](n+1)
        if (n < NVAR - 2) {
            stage_xb(cur, xp);
            if (n < NVAR - 3) xp = *(const float4*)(xrow + (n + 3) * DDIM);
        }
        if (n < NVAR - 1) prefetch_wb0(n + 1);
        __syncthreads();
    }

    // epilogue LN(15): red2[1], comb(15)
    {
        const int pn = NVAR - 1;
        const float* gma = vg_gamma + pn * 256;
        const float* bta = vg_beta + pn * 256;
#pragma unroll
        for (int i = 0; i < 2; ++i)
#pragma unroll
            for (int q = 0; q < 4; ++q) {
                int row = i * 16 + lc * 4 + q;
                const float4* rp = (const float4*)&red2[1][row][0][0];
                float4 r0 = rp[0], r1 = rp[1], r2 = rp[2], r3 = rp[3];
                float s  = r0.x + r0.z + r1.x + r1.z + r2.x + r2.z + r3.x + r3.z;
                float ss = r0.y + r0.w + r1.y + r1.w + r2.y + r2.w + r3.y + r3.w;
                float mean = s * (1.f / 256.f);
                float var  = ss * (1.f / 256.f) - mean * mean;
                float rstd = rsqrtf(var + 1e-5f);
                float wv = wls[row * 16 + pn];
#pragma unroll
                for (int j = 0; j < 2; ++j) {
                    int col = w * 32 + j * 16 + lr;
                    float pv = (comb[j][i][q] - mean) * rstd * gma[col] + bta[col];
                    selv[j][i][q] += wv * pv;
                }
            }
    }

    // ======== output GRN (identity skip = selv regs) ========
    __syncthreads();
#pragma unroll
    for (int j = 0; j < 2; ++j) {
        int col = w * 32 + j * 16 + lr;
#pragma unroll
        for (int i = 0; i < 2; ++i)
#pragma unroll
            for (int q = 0; q < 4; ++q) {
                int row = i * 16 + lc * 4 + q;
                hbuf[0][row * 256 + (HCHUNK(col >> 3, row) << 3) + (col & 7)] = (__bf16)selv[j][i][q];
            }
    }
    __syncthreads();

    // GEMM1': hbuf[1] = elu(selb @ ogW1 + og_b1)
    {
        f32x4 acc[2][2] = {};
#pragma unroll
        for (int kt = 0; kt < 8; ++kt) {
            bf16x8 bw0 = *(const bf16x8*)&ogW1p[(size_t)((w * 2 + 0) * 8 + kt) * 512 + lane * 8];
            bf16x8 bw1 = *(const bf16x8*)&ogW1p[(size_t)((w * 2 + 1) * 8 + kt) * 512 + lane * 8];
            bf16x8 af[2];
#pragma unroll
            for (int i = 0; i < 2; ++i) {
                int r = i * 16 + lr;
                int kc = HCHUNK(kt * 4 + lc, r);
                af[i] = *(const bf16x8*)&hbuf[0][r * 256 + kc * 8];
            }
            __builtin_amdgcn_s_setprio(1);
#pragma unroll
            for (int i = 0; i < 2; ++i) {
                acc[0][i] = __builtin_amdgcn_mfma_f32_16x16x32_bf16(af[i], bw0, acc[0][i], 0, 0, 0);
                acc[1][i] = __builtin_amdgcn_mfma_f32_16x16x32_bf16(af[i], bw1, acc[1][i], 0, 0, 0);
            }
            __builtin_amdgcn_s_setprio(0);
        }
#pragma unroll
        for (int j = 0; j < 2; ++j) {
            int col = w * 32 + j * 16 + lr;
            float bv = og_b1[col];
#pragma unroll
            for (int i = 0; i < 2; ++i)
#pragma unroll
                for (int q = 0; q < 4; ++q) {
                    int row = i * 16 + lc * 4 + q;
                    float x = acc[j][i][q] + bv;
                    x = x > 0.f ? x : (__expf(x) - 1.f);
                    hbuf[1][row * 256 + (HCHUNK(col >> 3, row) << 3) + (col & 7)] = (__bf16)x;
                }
        }
    }
    __syncthreads();

    // GEMM2': g5 = hbuf[1] @ ogWf; out = LN(selv + a*sig(g))
    {
        f32x4 aA[2][2] = {}, aG[2][2] = {};
#pragma unroll
        for (int kt = 0; kt < 8; ++kt) {
            bf16x8 ba0 = *(const bf16x8*)&ogWfp[(size_t)((w * 2 + 0) * 8 + kt) * 512 + lane * 8];
            bf16x8 ba1 = *(const bf16x8*)&ogWfp[(size_t)((w * 2 + 1) * 8 + kt) * 512 + lane * 8];
            bf16x8 bg0 = *(const bf16x8*)&ogWfp[(size_t)((16 + w * 2 + 0) * 8 + kt) * 512 + lane * 8];
            bf16x8 bg1 = *(const bf16x8*)&ogWfp[(size_t)((16 + w * 2 + 1) * 8 + kt) * 512 + lane * 8];
            bf16x8 af[2];
#pragma unroll
            for (int i = 0; i < 2; ++i) {
                int r = i * 16 + lr;
                int kc = HCHUNK(kt * 4 + lc, r);
                af[i] = *(const bf16x8*)&hbuf[1][r * 256 + kc * 8];
            }
            __builtin_amdgcn_s_setprio(1);
#pragma unroll
            for (int i = 0; i < 2; ++i) {
                aA[0][i] = __builtin_amdgcn_mfma_f32_16x16x32_bf16(af[i], ba0, aA[0][i], 0, 0, 0);
                aA[1][i] = __builtin_amdgcn_mfma_f32_16x16x32_bf16(af[i], ba1, aA[1][i], 0, 0, 0);
                aG[0][i] = __builtin_amdgcn_mfma_f32_16x16x32_bf16(af[i], bg0, aG[0][i], 0, 0, 0);
                aG[1][i] = __builtin_amdgcn_mfma_f32_16x16x32_bf16(af[i], bg1, aG[1][i], 0, 0, 0);
            }
            __builtin_amdgcn_s_setprio(0);
        }
#pragma unroll
        for (int j = 0; j < 2; ++j) {
            int col = w * 32 + j * 16 + lr;
            float ba_ = ogbWf[col], bg_ = ogbWf[col + 256];
#pragma unroll
            for (int i = 0; i < 2; ++i)
#pragma unroll
                for (int q = 0; q < 4; ++q) {
                    float av = aA[j][i][q] + ba_;
                    float gv = aG[j][i][q] + bg_;
                    comb[j][i][q] = selv[j][i][q] + av * (1.f / (1.f + __expf(-gv)));
                }
        }
#pragma unroll
        for (int i = 0; i < 2; ++i)
#pragma unroll
            for (int q = 0; q < 4; ++q) {
                float s = comb[0][i][q] + comb[1][i][q];
                float ss = comb[0][i][q] * comb[0][i][q] + comb[1][i][q] * comb[1][i][q];
                s += __shfl_xor(s, 1); ss += __shfl_xor(ss, 1);
                s += __shfl_xor(s, 2); ss += __shfl_xor(ss, 2);
                s += __shfl_xor(s, 4); ss += __shfl_xor(ss, 4);
                s += __shfl_xor(s, 8); ss += __shfl_xor(ss, 8);
                if (lr == 0) {
                    int row = i * 16 + lc * 4 + q;
                    red2[0][row][w][0] = s; red2[0][row][w][1] = ss;
                }
            }
        __syncthreads();
#pragma unroll
        for (int i = 0; i < 2; ++i)
#pragma unroll
            for (int q = 0; q < 4; ++q) {
                int row = i * 16 + lc * 4 + q;
                const float4* rp = (const float4*)&red2[0][row][0][0];
                float4 r0 = rp[0], r1 = rp[1], r2 = rp[2], r3 = rp[3];
                float s  = r0.x + r0.z + r1.x + r1.z + r2.x + r2.z + r3.x + r3.z;
                float ss = r0.y + r0.w + r1.y + r1.w + r2.y + r2.w + r3.y + r3.w;
                float mean = s * (1.f / 256.f);
                float var  = ss * (1.f / 256.f) - mean * mean;
                float rstd = rsqrtf(var + 1e-5f);
#pragma unroll
                for (int j = 0; j < 2; ++j) {
                    int col = w * 32 + j * 16 + lr;
                    out[(row0 + row) * 256 + col] = (comb[j][i][q] - mean) * rstd * og_gamma[col] + og_beta[col];
                }
            }
    }
}

// ---------------------------------------------------------------------------
extern "C" void kernel_launch(void* const* d_in, const int* in_sizes, int n_in,
                              void* d_out, int out_size, void* d_ws, size_t ws_size,
                              hipStream_t stream)
{
    const float* vars     = (const float*)d_in[0];
    const float* ctx      = (const float*)d_in[1];
    const float* fg_W1    = (const float*)d_in[2];
    const float* fg_b1    = (const float*)d_in[3];
    const float* fg_Wc    = (const float*)d_in[4];
    const float* fg_W2    = (const float*)d_in[5];
    const float* fg_b2    = (const float*)d_in[6];
    const float* fg_Wg    = (const float*)d_in[7];
    const float* fg_bg    = (const float*)d_in[8];
    const float* fg_skipW = (const float*)d_in[9];
    const float* fg_skipb = (const float*)d_in[10];
    const float* fg_gamma = (const float*)d_in[11];
    const float* fg_beta  = (const float*)d_in[12];
    const float* vg_W1    = (const float*)d_in[13];
    const float* vg_b1    = (const float*)d_in[14];
    const float* vg_W2    = (const float*)d_in[15];
    const float* vg_b2    = (const float*)d_in[16];
    const float* vg_Wg    = (const float*)d_in[17];
    const float* vg_bg    = (const float*)d_in[18];
    const float* vg_skipW = (const float*)d_in[19];
    const float* vg_skipb = (const float*)d_in[20];
    const float* vg_gamma = (const float*)d_in[21];
    const float* vg_beta  = (const float*)d_in[22];
    const float* og_W1    = (const float*)d_in[23];
    const float* og_b1    = (const float*)d_in[24];
    const float* og_W2    = (const float*)d_in[25];
    const float* og_b2    = (const float*)d_in[26];
    const float* og_Wg    = (const float*)d_in[27];
    const float* og_bg    = (const float*)d_in[28];
    const float* og_gamma = (const float*)d_in[29];
    const float* og_beta  = (const float*)d_in[30];

    float* out = (float*)d_out;
    float* wsm = out + (long)BT * ODIM;

    // ---- workspace ----
    char* W = (char*)d_ws;
    size_t o = 0;
    auto alloc = [&](size_t b) { void* p = W + o; o += (b + 255) & ~(size_t)255; return p; };
    __bf16* WgT    = (__bf16*)alloc((size_t)17 * 131072 * 2);   // Wg^T [z][512][256]
    __bf16* Wfb    = (__bf16*)alloc((size_t)17 * 131072 * 2);   // Wf [z][256][512]
    __bf16* Wfp    = (__bf16*)alloc((size_t)17 * 131072 * 2);   // frag-packed (z=16 -> og)
    __bf16* ogW1p  = (__bf16*)alloc((size_t)65536 * 2);
    __bf16* W1Sp   = (__bf16*)alloc((size_t)16 * 32768 * 2);
    __bf16* Btk1   = (__bf16*)alloc((size_t)384 * 1024 * 2);
    float*  bias2  = (float*)alloc((size_t)128 * 4);
    float*  bWf    = (float*)alloc((size_t)16 * 512 * 4);
    float*  ogbWf  = (float*)alloc((size_t)512 * 4);
    float*  fgWf   = (float*)alloc((size_t)256 * 32 * 4);
    float*  fgbf   = (float*)alloc((size_t)32 * 4);
    float*  ctxh   = (float*)alloc((size_t)64 * 256 * 4);
    __bf16* h1     = (__bf16*)alloc((size_t)BT * 256 * 2);
    __bf16* skip16 = (__bf16*)alloc((size_t)BT * 128 * 2);
    __bf16* ogWfp  = Wfp + (size_t)16 * 131072;

    dim3 blk(256);
    const int NOSPLIT = 1 << 30;

    // ---- setup (1 prep kernel + 2 Wf GEMMs + 1 pack kernel) ----
    misc_prep<<<2630, blk, 0, stream>>>(fg_skipW, fg_skipb, Btk1, bias2,
                                        fg_W2, fg_Wg, fg_b2, fg_bg, fgWf, fgbf,
                                        vg_b2, vg_Wg, vg_bg, og_b2, og_Wg, og_bg,
                                        bWf, ogbWf, ctx, fg_Wc, ctxh,
                                        fg_W1, WgT);
    // Wf[z] = W2[z] @ WgT[z]^T  (vg: z=0..15 direct; og: z=16)
    gemm_mfma<1><<<dim3(4, 2, 16), blk, 0, stream>>>(vg_W2, WgT, nullptr, nullptr,
                                                     Wfb, nullptr, 256, 256, 256, 512, 0,
                                                     nullptr, 0, NOSPLIT, 65536, 131072, 131072);
    gemm_mfma<1><<<dim3(4, 2, 1), blk, 0, stream>>>(og_W2, WgT + (size_t)16 * 131072, nullptr, nullptr,
                                                    Wfb + (size_t)16 * 131072, nullptr, 256, 256, 256, 512, 0,
                                                    nullptr, 0, NOSPLIT, 0, 0, 0);
    frag_pack_all<<<1376, blk, 0, stream>>>(Wfb, Wfp, vg_W1, vg_skipW, W1Sp, og_W1, ogW1p);

    // ---- flatten GRN: h1 (cols 0..255, elu+ctx) | skip16 (cols 256..383) ----
    gemm_mfma<1><<<dim3(3, 128), blk, 0, stream>>>(vars, Btk1, fg_b1, bias2,
                                                   h1, skip16, FDIM, FDIM, FDIM, HDIM, 128,
                                                   ctxh, 1, 256, 0, 0, 0);
    k2_logits<<<BT / 4, blk, 0, stream>>>(h1, skip16, fgWf, fgbf, fg_gamma, fg_beta, wsm);

    // ---- fused per-variable + output GRN ----
    vsn_mega<<<512, 512, 0, stream>>>(vars, wsm, W1Sp, Wfp,
                                      vg_b1, vg_skipb, bWf, vg_gamma, vg_beta,
                                      ogW1p, ogWfp, og_b1, ogbWf, og_gamma, og_beta,
                                      out);
}

// Round 21
// 362.907 us; speedup vs baseline: 1.0271x; 1.0271x over previous
//
#include <hip/hip_runtime.h>
#include <hip/hip_bf16.h>

#define BT    16384
#define NVAR  16
#define DDIM  64
#define FDIM  1024
#define HDIM  256
#define ODIM  256
#define CDIM  64

typedef __bf16 bf16x8 __attribute__((ext_vector_type(8)));
typedef __bf16 bf16x4 __attribute__((ext_vector_type(4)));
typedef float  f32x4  __attribute__((ext_vector_type(4)));

__device__ __forceinline__ void gload16(const void* g, void* l) {
    __builtin_amdgcn_global_load_lds((const __attribute__((address_space(1))) void*)g,
                                     (__attribute__((address_space(3))) void*)l, 16, 0, 0);
}

// ---------------------------------------------------------------------------
// bf16 MFMA GEMM (128x128 tile, BK=64, 4 waves). AF32: A f32 reg-staged.
// Split-output: cols >= splitCol -> C2. z-batched.
// ---------------------------------------------------------------------------
template<int AF32>
__global__ __launch_bounds__(256)
void gemm_mfma(const void* __restrict__ Araw, const __bf16* __restrict__ Bt,
               const float* __restrict__ bias, const float* __restrict__ bias2,
               __bf16* __restrict__ C, __bf16* __restrict__ C2,
               int K, int lda, int ldb, int ldc, int ldc2,
               const float* __restrict__ rowAdd, int act, int splitCol,
               long zA, long zB, long zC)
{
    __shared__ char smem[32768];
    char* As = smem;
    char* Bs = smem + 16384;

    const int z = blockIdx.z;
    const __bf16* Btz = Bt + z * zB;

    const int tid  = threadIdx.x;
    const int lane = tid & 63;
    const int wid  = tid >> 6;
    const int wr   = wid >> 1, wc = wid & 1;
    const int lr   = lane & 15, lc = lane >> 4;
    const long row0 = (long)blockIdx.y * 128;
    const int  col0 = blockIdx.x * 128;
    const int ldsbase = (tid & ~63) << 4;

    f32x4 acc[4][4] = {};
    int rA[4], rB[4];
#pragma unroll
    for (int i = 0; i < 4; ++i) { rA[i] = wr * 64 + i * 16 + lr; rB[i] = wc * 64 + i * 16 + lr; }

    const int nk = K >> 6;
    for (int kt = 0; kt < nk; ++kt) {
        const int k0 = kt << 6;
        __syncthreads();
#pragma unroll
        for (int s = 0; s < 4; ++s) {
            int q  = s * 256 + tid;
            int r  = q >> 3, cs = q & 7;
            int cg = cs ^ (r & 7);
            if (AF32 != 0) {
                const float* src = (const float*)Araw + z * zA + (row0 + r) * (long)lda + k0 + (cg << 3);
                float4 u0 = *(const float4*)src;
                float4 u1 = *(const float4*)(src + 4);
                bf16x8 o;
                o[0] = (__bf16)u0.x; o[1] = (__bf16)u0.y; o[2] = (__bf16)u0.z; o[3] = (__bf16)u0.w;
                o[4] = (__bf16)u1.x; o[5] = (__bf16)u1.y; o[6] = (__bf16)u1.z; o[7] = (__bf16)u1.w;
                *(bf16x8*)(As + q * 16) = o;
            } else {
                gload16((const __bf16*)Araw + z * zA + (row0 + r) * (long)lda + k0 + (cg << 3),
                        As + (s << 12) + ldsbase);
            }
            gload16(Btz + (long)(col0 + r) * ldb + k0 + (cg << 3), Bs + (s << 12) + ldsbase);
        }
        __syncthreads();
#pragma unroll
        for (int ks = 0; ks < 2; ++ks) {
            bf16x8 af[4], bfr[4];
#pragma unroll
            for (int i = 0; i < 4; ++i) {
                int c = ks * 4 + lc;
                af[i]  = *(const bf16x8*)(As + rA[i] * 128 + ((c ^ (rA[i] & 7)) << 4));
                bfr[i] = *(const bf16x8*)(Bs + rB[i] * 128 + ((c ^ (rB[i] & 7)) << 4));
            }
#pragma unroll
            for (int i = 0; i < 4; ++i)
#pragma unroll
                for (int j = 0; j < 4; ++j)
                    acc[i][j] = __builtin_amdgcn_mfma_f32_16x16x32_bf16(af[i], bfr[j], acc[i][j], 0, 0, 0);
        }
    }

#pragma unroll
    for (int j = 0; j < 4; ++j) {
        int col = col0 + wc * 64 + j * 16 + lr;
        bool hi = col >= splitCol;
        float bv = hi ? bias2[col - splitCol] : (bias ? bias[col] : 0.f);
#pragma unroll
        for (int i = 0; i < 4; ++i) {
            f32x4 v = acc[i][j];
#pragma unroll
            for (int q = 0; q < 4; ++q) {
                long row = row0 + wr * 64 + i * 16 + lc * 4 + q;
                float x = v[q] + bv;
                if (rowAdd && !hi) x += rowAdd[(row >> 8) * (long)ldc + col];
                if (act && !hi)    x = x > 0.f ? x : (__expf(x) - 1.f);
                if (hi) C2[z * zC + row * (long)ldc2 + (col - splitCol)] = (__bf16)x;
                else    C [z * zC + row * (long)ldc  + col]              = (__bf16)x;
            }
        }
    }
}

// ---------------------------------------------------------------------------
// misc_prep (fused): pad_skip | fgfuse | bfuse | ctxh | W2cat | 3x transpose
// ---------------------------------------------------------------------------
__global__ __launch_bounds__(256)
void misc_prep(const float* __restrict__ fg_skipW, const float* __restrict__ fg_skipb,
               __bf16* __restrict__ Btk1, float* __restrict__ bias2,
               const float* __restrict__ fg_W2, const float* __restrict__ fg_Wg,
               const float* __restrict__ fg_b2, const float* __restrict__ fg_bg,
               float* __restrict__ fgWf, float* __restrict__ fgbf,
               const float* __restrict__ vg_b2, const float* __restrict__ vg_Wg,
               const float* __restrict__ vg_bg, const float* __restrict__ og_b2,
               const float* __restrict__ og_Wg, const float* __restrict__ og_bg,
               float* __restrict__ bWf, float* __restrict__ ogbWf,
               const float* __restrict__ ctx, const float* __restrict__ fg_Wc,
               float* __restrict__ ctxh,
               const float* __restrict__ vg_W2, const float* __restrict__ og_W2,
               float* __restrict__ W2cat,
               const float* __restrict__ fg_W1, __bf16* __restrict__ WgT)
{
    __shared__ float cs[4352];   // 17 KB: ctxh uses 4096; transposes use [32][33]
    int bx = blockIdx.x, tid = threadIdx.x;
    if (bx < 128) {                       // pad_skip
        int r = bx;
        for (int k = tid; k < 1024; k += 256)
            Btk1[(size_t)(256 + r) * 1024 + k] = (r < 16) ? (__bf16)fg_skipW[k * 16 + r] : (__bf16)0.f;
        if (tid == 0) bias2[r] = (r < 16) ? fg_skipb[r] : 0.f;
    } else if (bx < 160) {                // fgfuse
        int c = bx - 128, k = tid;
        float s = 0.f;
#pragma unroll
        for (int j = 0; j < 16; ++j) s = fmaf(fg_W2[k * 16 + j], fg_Wg[j * 32 + c], s);
        fgWf[k * 32 + c] = s;
        if (k == 0) {
            float t = fg_bg[c];
#pragma unroll
            for (int j = 0; j < 16; ++j) t = fmaf(fg_b2[j], fg_Wg[j * 32 + c], t);
            fgbf[c] = t;
        }
    } else if (bx < 194) {                // bfuse (34 blocks)
        int u = bx - 160;
        int n = u >> 1, c = (u & 1) * 256 + tid;
        const float* b2 = n < 16 ? vg_b2 + n * 256 : og_b2;
        const float* Wg = n < 16 ? vg_Wg + (size_t)n * 131072 : og_Wg;
        const float* bg = n < 16 ? vg_bg + n * 512 : og_bg;
        float* dst      = n < 16 ? bWf + n * 512 : ogbWf;
        float s = bg[c];
        for (int k = 0; k < 256; ++k) s = fmaf(b2[k], Wg[k * 512 + c], s);
        dst[c] = s;
    } else if (bx < 198) {                // ctxh (4 blocks of 64 cols)
        for (int i = tid; i < 4096; i += 256) cs[i] = ctx[i];
        __syncthreads();
        int col = (bx - 194) * 64 + (tid & 63);
        int r0 = (tid >> 6) * 16;
        for (int r = r0; r < r0 + 16; ++r) {
            float s = 0.f;
            for (int k = 0; k < 64; ++k) s = fmaf(cs[r * 64 + k], fg_Wc[k * 256 + col], s);
            ctxh[r * 256 + col] = s;
        }
    } else if (bx < 1286) {               // W2cat copy (1088 blocks)
        int idx = (bx - 198) * 1024 + tid * 4;
        const float* src = (idx < 16 * 65536) ? vg_W2 + idx : og_W2 + (idx - 16 * 65536);
        *(float4*)(W2cat + idx) = *(const float4*)src;
    } else {                              // weight transposes (2432 blocks)
        int b2 = bx - 1286;
        const float* in; __bf16* outp; int K, N, tilesN, tl;
        if (b2 < 2048) {                  // vg_Wg [z][256][512] -> WgT [z][512][256]
            int z = b2 >> 7; tl = b2 & 127;
            in = vg_Wg + (size_t)z * 131072; outp = WgT + (size_t)z * 131072;
            K = 256; N = 512; tilesN = 16;
        } else if (b2 < 2176) {           // og_Wg -> WgT[16]
            tl = b2 - 2048;
            in = og_Wg; outp = WgT + (size_t)16 * 131072;
            K = 256; N = 512; tilesN = 16;
        } else {                          // fg_W1 [1024][256] -> Btk1 rows 0..255
            tl = b2 - 2176;
            in = fg_W1; outp = Btk1;
            K = 1024; N = 256; tilesN = 8;
        }
        int tk = tl / tilesN, tn = tl % tilesN;
        float (*t)[33] = (float(*)[33])cs;
        int r = tid >> 3, c0 = (tid & 7) << 2;
        float4 v = *(const float4*)(in + (size_t)(tk * 32 + r) * N + tn * 32 + c0);
        t[r][c0] = v.x; t[r][c0 + 1] = v.y; t[r][c0 + 2] = v.z; t[r][c0 + 3] = v.w;
        __syncthreads();
        int nn = tid >> 3, k4 = (tid & 7) << 2;
        bf16x4 o;
        o[0] = (__bf16)t[k4 + 0][nn]; o[1] = (__bf16)t[k4 + 1][nn];
        o[2] = (__bf16)t[k4 + 2][nn]; o[3] = (__bf16)t[k4 + 3][nn];
        *(bf16x4*)(outp + (size_t)(tn * 32 + nn) * K + tk * 32 + k4) = o;
    }
}

// ---------------------------------------------------------------------------
// frag_pack_all: 4 tiles/block (one per wave). t<4352: Wfb->Wfp (z 0..16);
// t<5376: W1S pack; t<5504: og_W1 pack.
// ---------------------------------------------------------------------------
__global__ __launch_bounds__(256)
void frag_pack_all(const __bf16* __restrict__ Wfb, __bf16* __restrict__ Wfp,
                   const float* __restrict__ vg_W1, const float* __restrict__ vg_skipW,
                   __bf16* __restrict__ W1Sp,
                   const float* __restrict__ og_W1, __bf16* __restrict__ ogW1p)
{
    int t = blockIdx.x * 4 + (threadIdx.x >> 6);
    int lane = threadIdx.x & 63, lr = lane & 15, lc = lane >> 4;
    if (t < 4352) {
        int z = t >> 8, b = t & 255;
        int nt = b >> 3, kt = b & 7;
        const __bf16* src = Wfb + (size_t)z * 131072;
        bf16x8 o;
#pragma unroll
        for (int e = 0; e < 8; ++e)
            o[e] = src[(size_t)(kt * 32 + lc * 8 + e) * 512 + nt * 16 + lr];
        *(bf16x8*)&Wfp[(size_t)z * 131072 + (size_t)b * 512 + lane * 8] = o;
    } else if (t < 5376) {
        int u = t - 4352; int n = u >> 6, b = u & 63;
        int nt = b >> 1, kt = b & 1;
        const float* src = (nt < 16) ? vg_W1 + (size_t)n * 16384 : vg_skipW + (size_t)n * 16384;
        int col = (nt & 15) * 16 + lr;
        bf16x8 o;
#pragma unroll
        for (int e = 0; e < 8; ++e)
            o[e] = (__bf16)src[(size_t)(kt * 32 + lc * 8 + e) * 256 + col];
        *(bf16x8*)&W1Sp[((size_t)n * 64 + b) * 512 + lane * 8] = o;
    } else if (t < 5504) {
        int b = t - 5376;
        int nt = b >> 3, kt = b & 7;
        bf16x8 o;
#pragma unroll
        for (int e = 0; e < 8; ++e)
            o[e] = (__bf16)og_W1[(size_t)(kt * 32 + lc * 8 + e) * 256 + nt * 16 + lr];
        *(bf16x8*)&ogW1p[(size_t)b * 512 + lane * 8] = o;
    }
}

// ---------------------------------------------------------------------------
// K2: g = h1@fgWf + skip16; LN16 + softmax16 -> w. 4 rows/block.
// ---------------------------------------------------------------------------
__global__ __launch_bounds__(256)
void k2_logits(const __bf16* __restrict__ h1, const __bf16* __restrict__ skip16,
               const float* __restrict__ Wf, const float* __restrict__ bf,
               const float* __restrict__ gamma, const float* __restrict__ beta,
               float* __restrict__ wout)
{
    __shared__ float hrow[4][256];
    int l = threadIdx.x & 63, wv_ = threadIdx.x >> 6;
    long row = (long)blockIdx.x * 4 + wv_;

    bf16x4 hv = *(const bf16x4*)(h1 + row * 256 + l * 4);
    float4 hf; hf.x = (float)hv[0]; hf.y = (float)hv[1]; hf.z = (float)hv[2]; hf.w = (float)hv[3];
    *(float4*)&hrow[wv_][l * 4] = hf;

    int cc = l & 31, half = l >> 5;
    float g = 0.f;
    int kb = half * 128;
#pragma unroll 4
    for (int k = kb; k < kb + 128; ++k)
        g = fmaf(hrow[wv_][k], Wf[k * 32 + cc], g);
    g += __shfl_xor(g, 32);
    g += bf[cc];

    int c = l & 15;
    float a2    = __shfl(g, c);
    float gate2 = __shfl(g, c + 16);
    float skip  = (float)skip16[row * 128 + c];
    float sv = skip + a2 * (1.f / (1.f + __expf(-gate2)));

    float sum = sv, sq = sv * sv;
#pragma unroll
    for (int m = 1; m < 16; m <<= 1) {
        sum += __shfl_xor(sum, m);
        sq  += __shfl_xor(sq, m);
    }
    float mean = sum * (1.f / 16.f);
    float var  = sq * (1.f / 16.f) - mean * mean;
    float logit = (sv - mean) * rsqrtf(var + 1e-5f) * gamma[c] + beta[c];

    float mx = logit;
#pragma unroll
    for (int m = 1; m < 16; m <<= 1) mx = fmaxf(mx, __shfl_xor(mx, m));
    float e = __expf(logit - mx);
    float es = e;
#pragma unroll
    for (int m = 1; m < 16; m <<= 1) es += __shfl_xor(es, m);
    if (l < 16) wout[row * NVAR + l] = e / es;
}

// hbuf swizzle: full 32-bank spread (adds row bit-3 into chunk XOR)
#define HCHUNK(c, r) ((c) ^ ((r) & 7) ^ ((((r) >> 3) & 1) << 1))

// ---------------------------------------------------------------------------
// MEGA v16 (R19 best, 289 us): 1 barrier/n pipeline, weight dbuf,
// cross-barrier wb0 prefetch, vectorized LN reads, 32-bank hbuf swizzle.
// ---------------------------------------------------------------------------
__global__ __launch_bounds__(512, 2)
void vsn_mega(const float* __restrict__ vars, const float* __restrict__ wsm,
              const __bf16* __restrict__ W1Sp, const __bf16* __restrict__ Wfp,
              const float* __restrict__ vg_b1, const float* __restrict__ vg_skipb,
              const float* __restrict__ bWf,
              const float* __restrict__ vg_gamma, const float* __restrict__ vg_beta,
              const __bf16* __restrict__ ogW1p, const __bf16* __restrict__ ogWfp,
              const float* __restrict__ og_b1, const float* __restrict__ ogbWf,
              const float* __restrict__ og_gamma, const float* __restrict__ og_beta,
              float* __restrict__ out)
{
    __shared__ __bf16 xb[2][32 * 64];      //  8 KB
    __shared__ __bf16 hbuf[2][32 * 256];   // 32 KB
    __shared__ float  red2[2][32][8][2];   //  4 KB
    __shared__ float  wls[32 * 16];        //  2 KB   => ~46 KB

    const int tid = threadIdx.x;
    const int w   = tid >> 6, lane = tid & 63;
    const int lr  = lane & 15, lc = lane >> 4;
    const long row0 = (long)blockIdx.x * 32;

    wls[tid] = wsm[row0 * 16 + tid];

    f32x4 selv[2][2] = {};    // [j][i]
    f32x4 skipv[2][2];        // [j][i] skip(n) carried across one barrier
    f32x4 comb[2][2];         // [j][i] combined(n) carried across one barrier
    bf16x8 wb[2][4];          // GEMM2 weight dbuf; wb[0] prefetched across barrier

    const int sr = tid >> 4, sc = tid & 15;
    const int shalf = sc & 1;
    const int scg = (sc >> 1) ^ (sr & 7);
    const float* xrow = vars + (row0 + sr) * FDIM + sc * 4;

    auto stage_xb = [&](int buf, float4 v) {
        bf16x4 o;
        o[0]=(__bf16)v.x; o[1]=(__bf16)v.y; o[2]=(__bf16)v.z; o[3]=(__bf16)v.w;
        *(bf16x4*)&xb[buf][sr * 64 + scg * 8 + shalf * 4] = o;
    };

    auto prefetch_wb0 = [&](int nn) {
        const __bf16* wfb = Wfp + (size_t)nn * 131072;
#pragma unroll
        for (int t = 0; t < 4; ++t) {
            int nt = (t < 2) ? (w * 2 + t) : (16 + w * 2 + (t - 2));
            wb[0][t] = *(const bf16x8*)&wfb[(size_t)(nt * 8 + 0) * 512 + lane * 8];
        }
    };

    // GEMM1(nn): read xb[buf] -> hbuf[buf] (elu) + skipv (regs)
    auto do_gemm1 = [&](int nn, int buf) {
        const __bf16* w1b = W1Sp + (size_t)nn * 32768;
        f32x4 accS[2][2] = {}, accH[2][2] = {};
#pragma unroll
        for (int kt = 0; kt < 2; ++kt) {
            bf16x8 wh0 = *(const bf16x8*)&w1b[(size_t)(((w * 2 + 0) * 2 + kt)) * 512 + lane * 8];
            bf16x8 wh1 = *(const bf16x8*)&w1b[(size_t)(((w * 2 + 1) * 2 + kt)) * 512 + lane * 8];
            bf16x8 ws0 = *(const bf16x8*)&w1b[(size_t)(((16 + w * 2 + 0) * 2 + kt)) * 512 + lane * 8];
            bf16x8 ws1 = *(const bf16x8*)&w1b[(size_t)(((16 + w * 2 + 1) * 2 + kt)) * 512 + lane * 8];
            bf16x8 af[2];
#pragma unroll
            for (int i = 0; i < 2; ++i) {
                int r = i * 16 + lr;
                int kc = (kt * 4 + lc) ^ (r & 7);
                af[i] = *(const bf16x8*)&xb[buf][r * 64 + kc * 8];
            }
            __builtin_amdgcn_s_setprio(1);
#pragma unroll
            for (int i = 0; i < 2; ++i) {
                accH[0][i] = __builtin_amdgcn_mfma_f32_16x16x32_bf16(af[i], wh0, accH[0][i], 0, 0, 0);
                accH[1][i] = __builtin_amdgcn_mfma_f32_16x16x32_bf16(af[i], wh1, accH[1][i], 0, 0, 0);
                accS[0][i] = __builtin_amdgcn_mfma_f32_16x16x32_bf16(af[i], ws0, accS[0][i], 0, 0, 0);
                accS[1][i] = __builtin_amdgcn_mfma_f32_16x16x32_bf16(af[i], ws1, accS[1][i], 0, 0, 0);
            }
            __builtin_amdgcn_s_setprio(0);
        }
        const float* b1 = vg_b1 + nn * 256;
        const float* sb = vg_skipb + nn * 256;
#pragma unroll
        for (int j = 0; j < 2; ++j) {
            int col = w * 32 + j * 16 + lr;
            float bh = b1[col], bs = sb[col];
#pragma unroll
            for (int i = 0; i < 2; ++i)
#pragma unroll
                for (int q = 0; q < 4; ++q) {
                    int row = i * 16 + lc * 4 + q;
                    float x = accH[j][i][q] + bh;
                    x = x > 0.f ? x : (__expf(x) - 1.f);
                    hbuf[buf][row * 256 + (HCHUNK(col >> 3, row) << 3) + (col & 7)] = (__bf16)x;
                    skipv[j][i][q] = accS[j][i][q] + bs;
                }
        }
    };

    // ---- prologue ----
    float4 xv = *(const float4*)(xrow);                 // x(0)
    stage_xb(0, xv);
    float4 xv1 = *(const float4*)(xrow + DDIM);         // x(1)
    __syncthreads();
    do_gemm1(0, 0);
    stage_xb(1, xv1);
    float4 xp = *(const float4*)(xrow + 2 * DDIM);      // x(2)
    prefetch_wb0(0);                                    // GEMM2(0) kt=0 weights
    __syncthreads();

    // ---- main pipeline: one barrier per n ----
    for (int n = 0; n < NVAR; ++n) {
        const int cur = n & 1, nxt = cur ^ 1;

        // 1. LN(n-1): red2[nxt] + comb -> selv
        if (n > 0) {
            const int pn = n - 1;
            const float* gma = vg_gamma + pn * 256;
            const float* bta = vg_beta + pn * 256;
#pragma unroll
            for (int i = 0; i < 2; ++i)
#pragma unroll
                for (int q = 0; q < 4; ++q) {
                    int row = i * 16 + lc * 4 + q;
                    const float4* rp = (const float4*)&red2[nxt][row][0][0];
                    float4 r0 = rp[0], r1 = rp[1], r2 = rp[2], r3 = rp[3];
                    float s  = r0.x + r0.z + r1.x + r1.z + r2.x + r2.z + r3.x + r3.z;
                    float ss = r0.y + r0.w + r1.y + r1.w + r2.y + r2.w + r3.y + r3.w;
                    float mean = s * (1.f / 256.f);
                    float var  = ss * (1.f / 256.f) - mean * mean;
                    float rstd = rsqrtf(var + 1e-5f);
                    float wv = wls[row * 16 + pn];
#pragma unroll
                    for (int j = 0; j < 2; ++j) {
                        int col = w * 32 + j * 16 + lr;
                        float pv = (comb[j][i][q] - mean) * rstd * gma[col] + bta[col];
                        selv[j][i][q] += wv * pv;
                    }
                }
        }

        // 2. GEMM2(n): hbuf[cur] @ Wf_n -> aA/aG  (wb[0] prefetched pre-barrier)
        {
            const __bf16* wfb = Wfp + (size_t)n * 131072;
            f32x4 aA[2][2] = {}, aG[2][2] = {};
#pragma unroll
            for (int kt = 0; kt < 8; ++kt) {
                const int cb = kt & 1, nb = cb ^ 1;
                if (kt < 7) {
#pragma unroll
                    for (int t = 0; t < 4; ++t) {
                        int nt = (t < 2) ? (w * 2 + t) : (16 + w * 2 + (t - 2));
                        wb[nb][t] = *(const bf16x8*)&wfb[(size_t)(nt * 8 + kt + 1) * 512 + lane * 8];
                    }
                }
                bf16x8 af[2];
#pragma unroll
                for (int i = 0; i < 2; ++i) {
                    int r = i * 16 + lr;
                    int kc = HCHUNK(kt * 4 + lc, r);
                    af[i] = *(const bf16x8*)&hbuf[cur][r * 256 + kc * 8];
                }
                __builtin_amdgcn_s_setprio(1);
#pragma unroll
                for (int i = 0; i < 2; ++i) {
                    aA[0][i] = __builtin_amdgcn_mfma_f32_16x16x32_bf16(af[i], wb[cb][0], aA[0][i], 0, 0, 0);
                    aA[1][i] = __builtin_amdgcn_mfma_f32_16x16x32_bf16(af[i], wb[cb][1], aA[1][i], 0, 0, 0);
                    aG[0][i] = __builtin_amdgcn_mfma_f32_16x16x32_bf16(af[i], wb[cb][2], aG[0][i], 0, 0, 0);
                    aG[1][i] = __builtin_amdgcn_mfma_f32_16x16x32_bf16(af[i], wb[cb][3], aG[1][i], 0, 0, 0);
                }
                __builtin_amdgcn_s_setprio(0);
            }
            // 3. combine with skipv(n); comb(n) = result; reduce -> red2[cur]
            const float* bW = bWf + n * 512;
#pragma unroll
            for (int j = 0; j < 2; ++j) {
                int col = w * 32 + j * 16 + lr;
                float ba_ = bW[col], bg_ = bW[col + 256];
#pragma unroll
                for (int i = 0; i < 2; ++i)
#pragma unroll
                    for (int q = 0; q < 4; ++q) {
                        float av = aA[j][i][q] + ba_;
                        float gv = aG[j][i][q] + bg_;
                        comb[j][i][q] = skipv[j][i][q] + av * (1.f / (1.f + __expf(-gv)));
                    }
            }
#pragma unroll
            for (int i = 0; i < 2; ++i)
#pragma unroll
                for (int q = 0; q < 4; ++q) {
                    float s = comb[0][i][q] + comb[1][i][q];
                    float ss = comb[0][i][q] * comb[0][i][q] + comb[1][i][q] * comb[1][i][q];
                    s += __shfl_xor(s, 1); ss += __shfl_xor(ss, 1);
                    s += __shfl_xor(s, 2); ss += __shfl_xor(ss, 2);
                    s += __shfl_xor(s, 4); ss += __shfl_xor(ss, 4);
                    s += __shfl_xor(s, 8); ss += __shfl_xor(ss, 8);
                    if (lr == 0) {
                        int row = i * 16 + lc * 4 + q;
                        red2[cur][row][w][0] = s; red2[cur][row][w][1] = ss;
                    }
                }
        }

        // 5. GEMM1(n+1) -> hbuf[nxt], skipv(n+1)
        if (n < NVAR - 1) do_gemm1(n + 1, nxt);

        // 6. stage x(n+2) into xb[cur]; prefetch x(n+3); prefetch wb[0](n+1)
        if (n < NVAR - 2) {
            stage_xb(cur, xp);
            if (n < NVAR - 3) xp = *(const float4*)(xrow + (n + 3) * DDIM);
        }
        if (n < NVAR - 1) prefetch_wb0(n + 1);
        __syncthreads();
    }

    // epilogue LN(15): red2[1], comb(15)
    {
        const int pn = NVAR - 1;
        const float* gma = vg_gamma + pn * 256;
        const float* bta = vg_beta + pn * 256;
#pragma unroll
        for (int i = 0; i < 2; ++i)
#pragma unroll
            for (int q = 0; q < 4; ++q) {
                int row = i * 16 + lc * 4 + q;
                const float4* rp = (const float4*)&red2[1][row][0][0];
                float4 r0 = rp[0], r1 = rp[1], r2 = rp[2], r3 = rp[3];
                float s  = r0.x + r0.z + r1.x + r1.z + r2.x + r2.z + r3.x + r3.z;
                float ss = r0.y + r0.w + r1.y + r1.w + r2.y + r2.w + r3.y + r3.w;
                float mean = s * (1.f / 256.f);
                float var  = ss * (1.f / 256.f) - mean * mean;
                float rstd = rsqrtf(var + 1e-5f);
                float wv = wls[row * 16 + pn];
#pragma unroll
                for (int j = 0; j < 2; ++j) {
                    int col = w * 32 + j * 16 + lr;
                    float pv = (comb[j][i][q] - mean) * rstd * gma[col] + bta[col];
                    selv[j][i][q] += wv * pv;
                }
            }
    }

    // ======== output GRN (identity skip = selv regs) ========
    __syncthreads();
#pragma unroll
    for (int j = 0; j < 2; ++j) {
        int col = w * 32 + j * 16 + lr;
#pragma unroll
        for (int i = 0; i < 2; ++i)
#pragma unroll
            for (int q = 0; q < 4; ++q) {
                int row = i * 16 + lc * 4 + q;
                hbuf[0][row * 256 + (HCHUNK(col >> 3, row) << 3) + (col & 7)] = (__bf16)selv[j][i][q];
            }
    }
    __syncthreads();

    // GEMM1': hbuf[1] = elu(selb @ ogW1 + og_b1)
    {
        f32x4 acc[2][2] = {};
#pragma unroll
        for (int kt = 0; kt < 8; ++kt) {
            bf16x8 bw0 = *(const bf16x8*)&ogW1p[(size_t)((w * 2 + 0) * 8 + kt) * 512 + lane * 8];
            bf16x8 bw1 = *(const bf16x8*)&ogW1p[(size_t)((w * 2 + 1) * 8 + kt) * 512 + lane * 8];
            bf16x8 af[2];
#pragma unroll
            for (int i = 0; i < 2; ++i) {
                int r = i * 16 + lr;
                int kc = HCHUNK(kt * 4 + lc, r);
                af[i] = *(const bf16x8*)&hbuf[0][r * 256 + kc * 8];
            }
            __builtin_amdgcn_s_setprio(1);
#pragma unroll
            for (int i = 0; i < 2; ++i) {
                acc[0][i] = __builtin_amdgcn_mfma_f32_16x16x32_bf16(af[i], bw0, acc[0][i], 0, 0, 0);
                acc[1][i] = __builtin_amdgcn_mfma_f32_16x16x32_bf16(af[i], bw1, acc[1][i], 0, 0, 0);
            }
            __builtin_amdgcn_s_setprio(0);
        }
#pragma unroll
        for (int j = 0; j < 2; ++j) {
            int col = w * 32 + j * 16 + lr;
            float bv = og_b1[col];
#pragma unroll
            for (int i = 0; i < 2; ++i)
#pragma unroll
                for (int q = 0; q < 4; ++q) {
                    int row = i * 16 + lc * 4 + q;
                    float x = acc[j][i][q] + bv;
                    x = x > 0.f ? x : (__expf(x) - 1.f);
                    hbuf[1][row * 256 + (HCHUNK(col >> 3, row) << 3) + (col & 7)] = (__bf16)x;
                }
        }
    }
    __syncthreads();

    // GEMM2': g5 = hbuf[1] @ ogWf; out = LN(selv + a*sig(g))
    {
        f32x4 aA[2][2] = {}, aG[2][2] = {};
#pragma unroll
        for (int kt = 0; kt < 8; ++kt) {
            bf16x8 ba0 = *(const bf16x8*)&ogWfp[(size_t)((w * 2 + 0) * 8 + kt) * 512 + lane * 8];
            bf16x8 ba1 = *(const bf16x8*)&ogWfp[(size_t)((w * 2 + 1) * 8 + kt) * 512 + lane * 8];
            bf16x8 bg0 = *(const bf16x8*)&ogWfp[(size_t)((16 + w * 2 + 0) * 8 + kt) * 512 + lane * 8];
            bf16x8 bg1 = *(const bf16x8*)&ogWfp[(size_t)((16 + w * 2 + 1) * 8 + kt) * 512 + lane * 8];
            bf16x8 af[2];
#pragma unroll
            for (int i = 0; i < 2; ++i) {
                int r = i * 16 + lr;
                int kc = HCHUNK(kt * 4 + lc, r);
                af[i] = *(const bf16x8*)&hbuf[1][r * 256 + kc * 8];
            }
            __builtin_amdgcn_s_setprio(1);
#pragma unroll
            for (int i = 0; i < 2; ++i) {
                aA[0][i] = __builtin_amdgcn_mfma_f32_16x16x32_bf16(af[i], ba0, aA[0][i], 0, 0, 0);
                aA[1][i] = __builtin_amdgcn_mfma_f32_16x16x32_bf16(af[i], ba1, aA[1][i], 0, 0, 0);
                aG[0][i] = __builtin_amdgcn_mfma_f32_16x16x32_bf16(af[i], bg0, aG[0][i], 0, 0, 0);
                aG[1][i] = __builtin_amdgcn_mfma_f32_16x16x32_bf16(af[i], bg1, aG[1][i], 0, 0, 0);
            }
            __builtin_amdgcn_s_setprio(0);
        }
#pragma unroll
        for (int j = 0; j < 2; ++j) {
            int col = w * 32 + j * 16 + lr;
            float ba_ = ogbWf[col], bg_ = ogbWf[col + 256];
#pragma unroll
            for (int i = 0; i < 2; ++i)
#pragma unroll
                for (int q = 0; q < 4; ++q) {
                    float av = aA[j][i][q] + ba_;
                    float gv = aG[j][i][q] + bg_;
                    comb[j][i][q] = selv[j][i][q] + av * (1.f / (1.f + __expf(-gv)));
                }
        }
#pragma unroll
        for (int i = 0; i < 2; ++i)
#pragma unroll
            for (int q = 0; q < 4; ++q) {
                float s = comb[0][i][q] + comb[1][i][q];
                float ss = comb[0][i][q] * comb[0][i][q] + comb[1][i][q] * comb[1][i][q];
                s += __shfl_xor(s, 1); ss += __shfl_xor(ss, 1);
                s += __shfl_xor(s, 2); ss += __shfl_xor(ss, 2);
                s += __shfl_xor(s, 4); ss += __shfl_xor(ss, 4);
                s += __shfl_xor(s, 8); ss += __shfl_xor(ss, 8);
                if (lr == 0) {
                    int row = i * 16 + lc * 4 + q;
                    red2[0][row][w][0] = s; red2[0][row][w][1] = ss;
                }
            }
        __syncthreads();
#pragma unroll
        for (int i = 0; i < 2; ++i)
#pragma unroll
            for (int q = 0; q < 4; ++q) {
                int row = i * 16 + lc * 4 + q;
                const float4* rp = (const float4*)&red2[0][row][0][0];
                float4 r0 = rp[0], r1 = rp[1], r2 = rp[2], r3 = rp[3];
                float s  = r0.x + r0.z + r1.x + r1.z + r2.x + r2.z + r3.x + r3.z;
                float ss = r0.y + r0.w + r1.y + r1.w + r2.y + r2.w + r3.y + r3.w;
                float mean = s * (1.f / 256.f);
                float var  = ss * (1.f / 256.f) - mean * mean;
                float rstd = rsqrtf(var + 1e-5f);
#pragma unroll
                for (int j = 0; j < 2; ++j) {
                    int col = w * 32 + j * 16 + lr;
                    out[(row0 + row) * 256 + col] = (comb[j][i][q] - mean) * rstd * og_gamma[col] + og_beta[col];
                }
            }
    }
}

// ---------------------------------------------------------------------------
extern "C" void kernel_launch(void* const* d_in, const int* in_sizes, int n_in,
                              void* d_out, int out_size, void* d_ws, size_t ws_size,
                              hipStream_t stream)
{
    const float* vars     = (const float*)d_in[0];
    const float* ctx      = (const float*)d_in[1];
    const float* fg_W1    = (const float*)d_in[2];
    const float* fg_b1    = (const float*)d_in[3];
    const float* fg_Wc    = (const float*)d_in[4];
    const float* fg_W2    = (const float*)d_in[5];
    const float* fg_b2    = (const float*)d_in[6];
    const float* fg_Wg    = (const float*)d_in[7];
    const float* fg_bg    = (const float*)d_in[8];
    const float* fg_skipW = (const float*)d_in[9];
    const float* fg_skipb = (const float*)d_in[10];
    const float* fg_gamma = (const float*)d_in[11];
    const float* fg_beta  = (const float*)d_in[12];
    const float* vg_W1    = (const float*)d_in[13];
    const float* vg_b1    = (const float*)d_in[14];
    const float* vg_W2    = (const float*)d_in[15];
    const float* vg_b2    = (const float*)d_in[16];
    const float* vg_Wg    = (const float*)d_in[17];
    const float* vg_bg    = (const float*)d_in[18];
    const float* vg_skipW = (const float*)d_in[19];
    const float* vg_skipb = (const float*)d_in[20];
    const float* vg_gamma = (const float*)d_in[21];
    const float* vg_beta  = (const float*)d_in[22];
    const float* og_W1    = (const float*)d_in[23];
    const float* og_b1    = (const float*)d_in[24];
    const float* og_W2    = (const float*)d_in[25];
    const float* og_b2    = (const float*)d_in[26];
    const float* og_Wg    = (const float*)d_in[27];
    const float* og_bg    = (const float*)d_in[28];
    const float* og_gamma = (const float*)d_in[29];
    const float* og_beta  = (const float*)d_in[30];

    float* out = (float*)d_out;
    float* wsm = out + (long)BT * ODIM;

    // ---- workspace ----
    char* W = (char*)d_ws;
    size_t o = 0;
    auto alloc = [&](size_t b) { void* p = W + o; o += (b + 255) & ~(size_t)255; return p; };
    __bf16* WgT    = (__bf16*)alloc((size_t)17 * 131072 * 2);   // Wg^T [z][512][256]
    __bf16* Wfb    = (__bf16*)alloc((size_t)17 * 131072 * 2);   // Wf [z][256][512]
    __bf16* Wfp    = (__bf16*)alloc((size_t)17 * 131072 * 2);   // frag-packed (z=16 -> og)
    __bf16* ogW1p  = (__bf16*)alloc((size_t)65536 * 2);
    __bf16* W1Sp   = (__bf16*)alloc((size_t)16 * 32768 * 2);
    __bf16* Btk1   = (__bf16*)alloc((size_t)384 * 1024 * 2);
    float*  W2cat  = (float*)alloc((size_t)17 * 65536 * 4);
    float*  bias2  = (float*)alloc((size_t)128 * 4);
    float*  bWf    = (float*)alloc((size_t)16 * 512 * 4);
    float*  ogbWf  = (float*)alloc((size_t)512 * 4);
    float*  fgWf   = (float*)alloc((size_t)256 * 32 * 4);
    float*  fgbf   = (float*)alloc((size_t)32 * 4);
    float*  ctxh   = (float*)alloc((size_t)64 * 256 * 4);
    __bf16* h1     = (__bf16*)alloc((size_t)BT * 256 * 2);
    __bf16* skip16 = (__bf16*)alloc((size_t)BT * 128 * 2);
    __bf16* ogWfp  = Wfp + (size_t)16 * 131072;

    dim3 blk(256);
    const int NOSPLIT = 1 << 30;

    // ---- setup (fused: 1 prep kernel + 1 GEMM + 1 pack kernel) ----
    misc_prep<<<3718, blk, 0, stream>>>(fg_skipW, fg_skipb, Btk1, bias2,
                                        fg_W2, fg_Wg, fg_b2, fg_bg, fgWf, fgbf,
                                        vg_b2, vg_Wg, vg_bg, og_b2, og_Wg, og_bg,
                                        bWf, ogbWf, ctx, fg_Wc, ctxh,
                                        vg_W2, og_W2, W2cat, fg_W1, WgT);
    // Wf[z] = W2cat[z] @ WgT[z]^T  (z = 0..16)
    gemm_mfma<1><<<dim3(4, 2, 17), blk, 0, stream>>>(W2cat, WgT, nullptr, nullptr,
                                                     Wfb, nullptr, 256, 256, 256, 512, 0,
                                                     nullptr, 0, NOSPLIT, 65536, 131072, 131072);
    frag_pack_all<<<1376, blk, 0, stream>>>(Wfb, Wfp, vg_W1, vg_skipW, W1Sp, og_W1, ogW1p);

    // ---- flatten GRN: h1 (cols 0..255, elu+ctx) | skip16 (cols 256..383) ----
    gemm_mfma<1><<<dim3(3, 128), blk, 0, stream>>>(vars, Btk1, fg_b1, bias2,
                                                   h1, skip16, FDIM, FDIM, FDIM, HDIM, 128,
                                                   ctxh, 1, 256, 0, 0, 0);
    k2_logits<<<BT / 4, blk, 0, stream>>>(h1, skip16, fgWf, fgbf, fg_gamma, fg_beta, wsm);

    // ---- fused per-variable + output GRN ----
    vsn_mega<<<512, 512, 0, stream>>>(vars, wsm, W1Sp, Wfp,
                                      vg_b1, vg_skipb, bWf, vg_gamma, vg_beta,
                                      ogW1p, ogWfp, og_b1, ogbWf, og_gamma, og_beta,
                                      out);
}